// Round 1
// baseline (2078.745 us; speedup 1.0000x reference)
//
#include <hip/hip_runtime.h>
#include <stdint.h>

#define NTOK 49
#define DIM 192
#define NHEADS 6
#define HD 32
#define QKV3 576
#define ATT_STRIDE 53   // odd -> conflict-free column access in softmax
#define QKV_STRIDE 36   // 72B rows: 8B aligned, 18-dword stride (breaks 16-bank aliasing)

__device__ __forceinline__ float bf2f(uint16_t u) {
    return __uint_as_float(((uint32_t)u) << 16);
}
__device__ __forceinline__ uint16_t f2bf(float f) {
    uint32_t u = __float_as_uint(f);
    uint32_t r = (u + 0x7FFFu + ((u >> 16) & 1u)) >> 16;  // round-to-nearest-even
    return (uint16_t)r;
}

__global__ __launch_bounds__(256)
void winattn_fused(const float* __restrict__ x,
                   const float* __restrict__ mask,
                   const float* __restrict__ w_qkv,
                   const float* __restrict__ b_qkv,
                   const float* __restrict__ w_proj,
                   const float* __restrict__ b_proj,
                   const float* __restrict__ table,
                   float* __restrict__ out)
{
    // LDS: 18816 + 3*3528 + 10388 + 18816 = 58604 B  -> 2 blocks/CU
    __shared__ uint16_t xs[NTOK][DIM];          // x tile, bf16
    __shared__ uint16_t qs[NTOK][QKV_STRIDE];   // per-head q (pre-scaled), bf16
    __shared__ uint16_t ks[NTOK][QKV_STRIDE];
    __shared__ uint16_t vs[NTOK][QKV_STRIDE];
    __shared__ float    attnS[NTOK][ATT_STRIDE];
    __shared__ uint16_t outS[NTOK][DIM];        // pre-proj attention output, bf16

    const int b = blockIdx.x;
    const int t = threadIdx.x;
    const float scale = 0.17677669529663687f;   // 32^-0.5

    // ---- load x tile: fp32 global -> bf16 LDS (float4 coalesced) ----
    {
        const float4* xb = (const float4*)(x + (size_t)b * (NTOK * DIM));
        for (int i = t; i < NTOK * DIM / 4; i += 256) {
            float4 v = xb[i];
            ushort4 s;
            s.x = f2bf(v.x); s.y = f2bf(v.y); s.z = f2bf(v.z); s.w = f2bf(v.w);
            *(ushort4*)(&xs[0][0] + i * 4) = s;
        }
    }
    __syncthreads();

    const int d  = t & 31;   // head-dim lane
    const int rg = t >> 5;   // row group 0..7
    const float* maskw = mask + (size_t)(b & 63) * (NTOK * NTOK);

    for (int h = 0; h < NHEADS; ++h) {
        // ================= Phase A: qkv GEMM for head h =================
        // thread (d, rg) computes q/k/v[r][d] for rows r = rg, rg+8, ...
        {
            const int cq = h * HD + d;          // q column in [0,576); k at +192, v at +384
            float aq[7], ak[7], av[7];
            #pragma unroll
            for (int i = 0; i < 7; ++i) { aq[i] = 0.f; ak[i] = 0.f; av[i] = 0.f; }

            for (int k = 0; k < DIM; k += 4) {
                float wq[4], wk[4], wv[4];
                #pragma unroll
                for (int j = 0; j < 4; ++j) {
                    const float* wr = w_qkv + (size_t)(k + j) * QKV3 + cq;
                    wq[j] = wr[0];
                    wk[j] = wr[DIM];
                    wv[j] = wr[2 * DIM];
                }
                #pragma unroll
                for (int i = 0; i < 7; ++i) {
                    int r  = rg + 8 * i;
                    int ra = (r < NTOK) ? r : (NTOK - 1);   // clamp: loads valid, result discarded
                    ushort4 xv = *(const ushort4*)&xs[ra][k];
                    float x0 = bf2f(xv.x), x1 = bf2f(xv.y), x2 = bf2f(xv.z), x3 = bf2f(xv.w);
                    aq[i] += x0 * wq[0] + x1 * wq[1] + x2 * wq[2] + x3 * wq[3];
                    ak[i] += x0 * wk[0] + x1 * wk[1] + x2 * wk[2] + x3 * wk[3];
                    av[i] += x0 * wv[0] + x1 * wv[1] + x2 * wv[2] + x3 * wv[3];
                }
            }
            const float bq = b_qkv[cq], bk = b_qkv[DIM + cq], bv = b_qkv[2 * DIM + cq];
            #pragma unroll
            for (int i = 0; i < 7; ++i) {
                int r = rg + 8 * i;
                if (r < NTOK) {
                    qs[r][d] = f2bf((aq[i] + bq) * scale);
                    ks[r][d] = f2bf(ak[i] + bk);
                    vs[r][d] = f2bf(av[i] + bv);
                }
            }
        }
        __syncthreads();

        // ================= Phase B1: logits = q @ k^T + bias + mask =================
        // 2-row register blocking: idx -> (r0, c), also does r0+25
        for (int idx = t; idx < 25 * NTOK; idx += 256) {
            int r0 = idx / NTOK;
            int c  = idx - r0 * NTOK;
            int r1 = r0 + 25;
            int r1a = (r1 < NTOK) ? r1 : 0;
            float s0 = 0.f, s1 = 0.f;
            #pragma unroll
            for (int kk = 0; kk < HD; kk += 4) {
                ushort4 kv = *(const ushort4*)&ks[c][kk];
                float k0 = bf2f(kv.x), k1 = bf2f(kv.y), k2 = bf2f(kv.z), k3 = bf2f(kv.w);
                ushort4 q0 = *(const ushort4*)&qs[r0][kk];
                s0 += bf2f(q0.x) * k0 + bf2f(q0.y) * k1 + bf2f(q0.z) * k2 + bf2f(q0.w) * k3;
                ushort4 q1 = *(const ushort4*)&qs[r1a][kk];
                s1 += bf2f(q1.x) * k0 + bf2f(q1.y) * k1 + bf2f(q1.z) * k2 + bf2f(q1.w) * k3;
            }
            int cm = c % 7, cd = c / 7;
            {
                int rm = r0 % 7, rd = r0 / 7;
                int bi = 13 * (rm - cm + 6) + (rd - cd + 6);
                attnS[r0][c] = s0 + table[bi * NHEADS + h] + maskw[r0 * NTOK + c];
            }
            if (r1 < NTOK) {
                int rm = r1 % 7, rd = r1 / 7;
                int bi = 13 * (rm - cm + 6) + (rd - cd + 6);
                attnS[r1][c] = s1 + table[bi * NHEADS + h] + maskw[r1 * NTOK + c];
            }
        }
        __syncthreads();

        // ================= Phase B2: softmax rows (4 lanes per row) =================
        {
            int r = t >> 2, sub = t & 3;
            if (r < NTOK) {
                float m = -1e30f;
                for (int c = sub; c < NTOK; c += 4) m = fmaxf(m, attnS[r][c]);
                m = fmaxf(m, __shfl_xor(m, 1));
                m = fmaxf(m, __shfl_xor(m, 2));
                float ssum = 0.f;
                for (int c = sub; c < NTOK; c += 4) {
                    float e = __expf(attnS[r][c] - m);
                    attnS[r][c] = e;
                    ssum += e;
                }
                ssum += __shfl_xor(ssum, 1);
                ssum += __shfl_xor(ssum, 2);
                float inv = 1.f / ssum;
                for (int c = sub; c < NTOK; c += 4) attnS[r][c] *= inv;
            }
        }
        __syncthreads();

        // ================= Phase B3: out_h = attn @ v =================
        for (int idx = t; idx < NTOK * HD; idx += 256) {
            int r  = idx >> 5;
            int dd = idx & 31;
            float s = 0.f;
            for (int c = 0; c < NTOK; ++c)
                s += attnS[r][c] * bf2f(vs[c][dd]);
            outS[r][h * HD + dd] = f2bf(s);
        }
        __syncthreads();   // protects qs/ks/vs/attnS for next head
    }

    // ================= Phase C: proj GEMM + bias, write global =================
    // 240 active threads: 48 col-groups (4 cols) x 5 row-groups (10 rows each)
    if (t < 240) {
        int cg  = t % 48;
        int rg5 = t / 48;
        int c0  = cg * 4;
        float4 bp = *(const float4*)&b_proj[c0];
        float acc[10][4];
        #pragma unroll
        for (int i = 0; i < 10; ++i) {
            acc[i][0] = bp.x; acc[i][1] = bp.y; acc[i][2] = bp.z; acc[i][3] = bp.w;
        }
        for (int k = 0; k < DIM; k += 2) {
            float4 w0 = *(const float4*)&w_proj[(size_t)k * DIM + c0];
            float4 w1 = *(const float4*)&w_proj[(size_t)(k + 1) * DIM + c0];
            #pragma unroll
            for (int i = 0; i < 10; ++i) {
                int r  = rg5 + 5 * i;
                int ra = (r < NTOK) ? r : (NTOK - 1);
                uint32_t pair = *(const uint32_t*)&outS[ra][k];
                float x0 = __uint_as_float(pair << 16);
                float x1 = __uint_as_float(pair & 0xFFFF0000u);
                acc[i][0] += x0 * w0.x + x1 * w1.x;
                acc[i][1] += x0 * w0.y + x1 * w1.y;
                acc[i][2] += x0 * w0.z + x1 * w1.z;
                acc[i][3] += x0 * w0.w + x1 * w1.w;
            }
        }
        float* ob = out + (size_t)b * (NTOK * DIM);
        #pragma unroll
        for (int i = 0; i < 10; ++i) {
            int r = rg5 + 5 * i;
            if (r < NTOK) {
                float4 v;
                v.x = acc[i][0]; v.y = acc[i][1]; v.z = acc[i][2]; v.w = acc[i][3];
                *(float4*)&ob[r * DIM + c0] = v;
            }
        }
    }
}

extern "C" void kernel_launch(void* const* d_in, const int* in_sizes, int n_in,
                              void* d_out, int out_size, void* d_ws, size_t ws_size,
                              hipStream_t stream) {
    const float* x      = (const float*)d_in[0];
    const float* mask   = (const float*)d_in[1];
    const float* w_qkv  = (const float*)d_in[2];
    const float* b_qkv  = (const float*)d_in[3];
    const float* w_proj = (const float*)d_in[4];
    const float* b_proj = (const float*)d_in[5];
    const float* table  = (const float*)d_in[6];
    float* out = (float*)d_out;

    const int nblocks = in_sizes[0] / (NTOK * DIM);   // 4096 windows
    winattn_fused<<<nblocks, 256, 0, stream>>>(x, mask, w_qkv, b_qkv,
                                               w_proj, b_proj, table, out);
}

// Round 2
// 837.968 us; speedup vs baseline: 2.4807x; 2.4807x over previous
//
#include <hip/hip_runtime.h>
#include <stdint.h>

#define NTOK 49
#define PM   64
#define DIM  192
#define QKV3 576
#define NHEADS 6
#define HD   32

typedef __attribute__((ext_vector_type(8))) short short8;
typedef __attribute__((ext_vector_type(4))) float f32x4;

__device__ __forceinline__ float bf2f(uint16_t u) {
    return __uint_as_float(((uint32_t)u) << 16);
}
__device__ __forceinline__ uint16_t f2bf(float f) {
    uint32_t u = __float_as_uint(f);
    return (uint16_t)((u + 0x7FFFu + ((u >> 16) & 1u)) >> 16);  // RNE
}

// ---- one-time weight transpose+cast: wqkvT[576][192], wprojT[192][192] (bf16) ----
__global__ void conv_weights(const float* __restrict__ wqkv,
                             const float* __restrict__ wproj,
                             uint16_t* __restrict__ ws) {
    int i = blockIdx.x * 256 + threadIdx.x;
    if (i < QKV3 * DIM) {
        int n = i / DIM, k = i - n * DIM;
        ws[i] = f2bf(wqkv[(size_t)k * QKV3 + n]);
    } else {
        int j = i - QKV3 * DIM;
        if (j < DIM * DIM) {
            int n = j / DIM, k = j - n * DIM;
            ws[QKV3 * DIM + j] = f2bf(wproj[(size_t)k * DIM + n]);
        }
    }
}

template <bool PRE>
__global__ __launch_bounds__(512, 2)
void winattn_mfma(const float* __restrict__ x,
                  const float* __restrict__ mask,
                  const float* __restrict__ w_qkv,
                  const float* __restrict__ b_qkv,
                  const float* __restrict__ w_proj,
                  const float* __restrict__ b_proj,
                  const float* __restrict__ table,
                  const uint16_t* __restrict__ wpre,
                  float* __restrict__ out)
{
    // LDS plan (130560 B total -> 1 block/CU, 8 waves):
    //   xls: x tile bf16 [64][200] during qkv; reused as ls fp32[64][66] + pa bf16[64][72]
    __shared__ __align__(16) uint16_t xls[13056];      // 26112 B
    __shared__ __align__(16) uint16_t qs [PM * 200];   // Q (pre-scaled) bf16
    __shared__ __align__(16) uint16_t ks_[PM * 200];   // K bf16
    __shared__ __align__(16) uint16_t vta[DIM * 72];   // V^T bf16: [h*32+d][token]
    __shared__ __align__(16) uint16_t os [PM * 200];   // attention output bf16

    float*    ls = (float*)xls;       // [64][66] fp32 = 16896 B
    uint16_t* pa = xls + 8448;        // [64][72] bf16 = 9216 B (offset 16896 B)

    const int b    = blockIdx.x;
    const int t    = threadIdx.x;
    const int wave = t >> 6;
    const int lane = t & 63;
    const int q4   = lane >> 4;       // quad 0..3
    const int l16  = lane & 15;
    const float SCALE = 0.17677669529663687f;

    const uint16_t* wqkvT  = wpre;                    // [576][192]
    const uint16_t* wprojT = wpre + QKV3 * DIM;       // [192][192]
    const float* maskw = mask + (size_t)(b & 63) * (NTOK * NTOK);

    // ---------- Phase 0: x -> bf16 LDS tile (rows 49..63 zero) ----------
    {
        const float4* xb = (const float4*)(x + (size_t)b * (NTOK * DIM));
        for (int i = t; i < NTOK * DIM / 4; i += 512) {
            float4 v = xb[i];
            int e = i * 4, r = e / DIM, c = e - r * DIM;
            ushort4 s;
            s.x = f2bf(v.x); s.y = f2bf(v.y); s.z = f2bf(v.z); s.w = f2bf(v.w);
            *(ushort4*)&xls[r * 200 + c] = s;
        }
        for (int i = t; i < 15 * DIM / 4; i += 512) {
            int r = 49 + i / (DIM / 4), c = (i % (DIM / 4)) * 4;
            *(ushort4*)&xls[r * 200 + c] = (ushort4){0, 0, 0, 0};
        }
    }
    __syncthreads();

    // ---------- preload A-fragments of x (all M-tiles, all K-steps) ----------
    short8 afrag[4][6];
    #pragma unroll
    for (int mt = 0; mt < 4; ++mt)
        #pragma unroll
        for (int kk = 0; kk < 6; ++kk)
            afrag[mt][kk] = *(const short8*)&xls[(mt * 16 + l16) * 200 + kk * 32 + q4 * 8];

    // ---------- Phase A: qkv GEMM (all heads), MFMA ----------
    for (int nt = wave; nt < 36; nt += 8) {
        const int col = nt * 16 + l16;  // 0..575
        f32x4 acc[4];
        #pragma unroll
        for (int mt = 0; mt < 4; ++mt) acc[mt] = (f32x4){0.f, 0.f, 0.f, 0.f};

        #pragma unroll
        for (int kk = 0; kk < 6; ++kk) {
            short8 bfrag;
            if (PRE) {
                bfrag = *(const short8*)&wqkvT[(size_t)col * DIM + kk * 32 + q4 * 8];
            } else {
                union { uint16_t u[8]; short8 v; } tb;
                int k0 = kk * 32 + q4 * 8;
                #pragma unroll
                for (int j = 0; j < 8; ++j) tb.u[j] = f2bf(w_qkv[(size_t)(k0 + j) * QKV3 + col]);
                bfrag = tb.v;
            }
            #pragma unroll
            for (int mt = 0; mt < 4; ++mt)
                acc[mt] = __builtin_amdgcn_mfma_f32_16x16x32_bf16(afrag[mt][kk], bfrag, acc[mt], 0, 0, 0);
        }
        const float bias = b_qkv[col];
        if (col < DIM) {              // Q: pre-scale
            #pragma unroll
            for (int mt = 0; mt < 4; ++mt)
                #pragma unroll
                for (int i = 0; i < 4; ++i)
                    qs[(mt * 16 + q4 * 4 + i) * 200 + col] = f2bf((acc[mt][i] + bias) * SCALE);
        } else if (col < 2 * DIM) {   // K
            #pragma unroll
            for (int mt = 0; mt < 4; ++mt)
                #pragma unroll
                for (int i = 0; i < 4; ++i)
                    ks_[(mt * 16 + q4 * 4 + i) * 200 + (col - DIM)] = f2bf(acc[mt][i] + bias);
        } else {                      // V -> transposed store
            const int vc = col - 2 * DIM;
            #pragma unroll
            for (int mt = 0; mt < 4; ++mt)
                #pragma unroll
                for (int i = 0; i < 4; ++i)
                    vta[vc * 72 + (mt * 16 + q4 * 4 + i)] = f2bf(acc[mt][i] + bias);
        }
    }
    __syncthreads();

    // zero pa rows 49..63 once (softmax rewrites rows<49 each head)
    for (int i = t; i < 15 * 72; i += 512) pa[(49 * 72) + i] = 0;

    // ---------- Phase B: per-head attention ----------
    for (int h = 0; h < NHEADS; ++h) {
        // B1: logits = Q_h @ K_h^T  (16 tiles; wave owns 2)
        #pragma unroll
        for (int s = 0; s < 2; ++s) {
            const int tid = wave * 2 + s;
            const int mt = tid >> 2, nt = tid & 3;
            short8 aq = *(const short8*)&qs [(mt * 16 + l16) * 200 + h * 32 + q4 * 8];
            short8 bk = *(const short8*)&ks_[(nt * 16 + l16) * 200 + h * 32 + q4 * 8];
            f32x4 c = (f32x4){0.f, 0.f, 0.f, 0.f};
            c = __builtin_amdgcn_mfma_f32_16x16x32_bf16(aq, bk, c, 0, 0, 0);
            const int cc = nt * 16 + l16;
            if (cc < NTOK) {
                const int cm = cc % 7, cd = cc / 7;
                #pragma unroll
                for (int i = 0; i < 4; ++i) {
                    const int r = mt * 16 + q4 * 4 + i;
                    if (r < NTOK) {
                        const int rm = r % 7, rd = r / 7;
                        const int bi = 13 * (rm - cm + 6) + (rd - cd + 6);
                        ls[r * 66 + cc] = c[i] + table[bi * NHEADS + h] + maskw[r * NTOK + cc];
                    }
                }
            }
        }
        __syncthreads();

        // B2: softmax (8 lanes per row)
        {
            const int r = t >> 3, sub = t & 7;
            if (r < NTOK) {
                float m = -1e30f;
                for (int c = sub; c < NTOK; c += 8) m = fmaxf(m, ls[r * 66 + c]);
                m = fmaxf(m, __shfl_xor(m, 1));
                m = fmaxf(m, __shfl_xor(m, 2));
                m = fmaxf(m, __shfl_xor(m, 4));
                float sum = 0.f;
                float ev[7]; int cnt = 0;
                for (int c = sub; c < NTOK; c += 8) {
                    float e = __expf(ls[r * 66 + c] - m);
                    ev[cnt++] = e; sum += e;
                }
                sum += __shfl_xor(sum, 1);
                sum += __shfl_xor(sum, 2);
                sum += __shfl_xor(sum, 4);
                const float inv = 1.f / sum;
                cnt = 0;
                for (int c = sub; c < PM; c += 8) {
                    uint16_t v = 0;
                    if (c < NTOK) v = f2bf(ev[cnt++] * inv);
                    pa[r * 72 + c] = v;
                }
            }
        }
        __syncthreads();

        // B3: out_h = P @ V_h  (8 tiles; 1 per wave, 2 K-steps)
        {
            const int mt = wave >> 1, nt = wave & 1;
            f32x4 c = (f32x4){0.f, 0.f, 0.f, 0.f};
            #pragma unroll
            for (int kk = 0; kk < 2; ++kk) {
                short8 ap = *(const short8*)&pa [(mt * 16 + l16) * 72 + kk * 32 + q4 * 8];
                short8 bv = *(const short8*)&vta[(h * 32 + nt * 16 + l16) * 72 + kk * 32 + q4 * 8];
                c = __builtin_amdgcn_mfma_f32_16x16x32_bf16(ap, bv, c, 0, 0, 0);
            }
            #pragma unroll
            for (int i = 0; i < 4; ++i)
                os[(mt * 16 + q4 * 4 + i) * 200 + h * 32 + nt * 16 + l16] = f2bf(c[i]);
        }
        // no barrier needed here: next-head B1 touches only ls/qs/ks (disjoint from pa/os);
        // the post-B1 barrier orders this head's B3 reads before next-head pa writes.
    }
    __syncthreads();

    // ---------- Phase C: proj GEMM + bias -> global ----------
    {
        float* ob = out + (size_t)b * (NTOK * DIM);
        for (int id = wave; id < 48; id += 8) {     // 48 tiles = 4 mt x 12 nt
            const int mt = id / 12, nt = id - mt * 12;
            const int col = nt * 16 + l16;
            f32x4 c = (f32x4){0.f, 0.f, 0.f, 0.f};
            #pragma unroll
            for (int kk = 0; kk < 6; ++kk) {
                short8 a = *(const short8*)&os[(mt * 16 + l16) * 200 + kk * 32 + q4 * 8];
                short8 bw;
                if (PRE) {
                    bw = *(const short8*)&wprojT[(size_t)col * DIM + kk * 32 + q4 * 8];
                } else {
                    union { uint16_t u[8]; short8 v; } tb;
                    int k0 = kk * 32 + q4 * 8;
                    #pragma unroll
                    for (int j = 0; j < 8; ++j) tb.u[j] = f2bf(w_proj[(size_t)(k0 + j) * DIM + col]);
                    bw = tb.v;
                }
                c = __builtin_amdgcn_mfma_f32_16x16x32_bf16(a, bw, c, 0, 0, 0);
            }
            const float bias = b_proj[col];
            #pragma unroll
            for (int i = 0; i < 4; ++i) {
                const int row = mt * 16 + q4 * 4 + i;
                if (row < NTOK) ob[row * DIM + col] = c[i] + bias;
            }
        }
    }
}

extern "C" void kernel_launch(void* const* d_in, const int* in_sizes, int n_in,
                              void* d_out, int out_size, void* d_ws, size_t ws_size,
                              hipStream_t stream) {
    const float* x      = (const float*)d_in[0];
    const float* mask   = (const float*)d_in[1];
    const float* w_qkv  = (const float*)d_in[2];
    const float* b_qkv  = (const float*)d_in[3];
    const float* w_proj = (const float*)d_in[4];
    const float* b_proj = (const float*)d_in[5];
    const float* table  = (const float*)d_in[6];
    float* out = (float*)d_out;

    const int nblocks = in_sizes[0] / (NTOK * DIM);   // 4096 windows
    const size_t WS_NEED = (size_t)(QKV3 * DIM + DIM * DIM) * sizeof(uint16_t);

    if (ws_size >= WS_NEED && d_ws != nullptr) {
        uint16_t* wpre = (uint16_t*)d_ws;
        const int total = QKV3 * DIM + DIM * DIM;     // 147456
        conv_weights<<<(total + 255) / 256, 256, 0, stream>>>(w_qkv, w_proj, wpre);
        winattn_mfma<true><<<nblocks, 512, 0, stream>>>(x, mask, w_qkv, b_qkv,
                                                        w_proj, b_proj, table, wpre, out);
    } else {
        winattn_mfma<false><<<nblocks, 512, 0, stream>>>(x, mask, w_qkv, b_qkv,
                                                         w_proj, b_proj, table, nullptr, out);
    }
}

// Round 3
// 565.063 us; speedup vs baseline: 3.6788x; 1.4830x over previous
//
#include <hip/hip_runtime.h>
#include <stdint.h>

#define NTOK 49
#define DIM  192
#define QKV3 576
#define NHEADS 6

typedef __attribute__((ext_vector_type(8))) short short8;
typedef __attribute__((ext_vector_type(4))) float f32x4;

__device__ __forceinline__ float bf2f(uint16_t u) {
    return __uint_as_float(((uint32_t)u) << 16);
}
__device__ __forceinline__ uint16_t f2bf(float f) {
    uint32_t u = __float_as_uint(f);
    return (uint16_t)((u + 0x7FFFu + ((u >> 16) & 1u)) >> 16);  // RNE
}

// XOR-swizzled element offset for stride-192 bf16 tiles (16B granules).
// Conflict-free for A/B-frag reads where row = l16 + const (granule ^ row&7).
__device__ __forceinline__ int swz(int row, int col) {
    return row * 192 + ((((col >> 3) ^ (row & 7)) << 3)) + (col & 7);
}
// Same for V^T tile: [d][64 tokens]
__device__ __forceinline__ int vswz(int d, int tok) {
    return d * 64 + ((((tok >> 3) ^ (d & 7)) << 3)) + (tok & 7);
}

// ---- prep: wqkvT[576][192] bf16, wprojT[192][192] bf16, biasT fp32 in C-frag order ----
#define NQ (QKV3 * DIM)          // 110592
#define NP (DIM * DIM)           // 36864
#define NB (NHEADS * 4 * 4 * 64 * 4)  // 24576
__global__ void prep_kernel(const float* __restrict__ wqkv,
                            const float* __restrict__ wproj,
                            const float* __restrict__ table,
                            uint16_t* __restrict__ ws) {
    int i = blockIdx.x * 256 + threadIdx.x;
    if (i < NQ) {
        int n = i / DIM, k = i - n * DIM;
        ws[i] = f2bf(wqkv[(size_t)k * QKV3 + n]);
    } else if (i < NQ + NP) {
        int j = i - NQ;
        int n = j / DIM, k = j - n * DIM;
        ws[NQ + j] = f2bf(wproj[(size_t)k * DIM + n]);
    } else if (i < NQ + NP + NB) {
        int e = i - NQ - NP;
        // layout [h][mt][nt][lane][i]
        int ii   = e & 3;
        int lane = (e >> 2) & 63;
        int nt   = (e >> 8) & 3;
        int mt   = (e >> 10) & 3;
        int h    = e >> 12;
        int r = mt * 16 + ((lane >> 4) << 2) + ii;
        int c = nt * 16 + (lane & 15);
        float val = 0.f;
        if (r < NTOK && c < NTOK) {
            int rm = r % 7, rd = r / 7, cm = c % 7, cd = c / 7;
            int bi = 13 * (rm - cm + 6) + (rd - cd + 6);
            val = table[bi * NHEADS + h];
        }
        ((float*)(ws + NQ + NP))[e] = val;
    }
}

// LDS element offsets (uint16 units). Total 40512 els = 81024 B -> 2 blocks/CU.
#define U_OFF   0        // x tile (49x192 swz) in phase A; per-wave pa (16x72) in phase B
#define QS_OFF  9408
#define KS_OFF  18816
#define VTA_OFF 28224    // 192x64
#define LDS_ELS 40512
#define PA_STR  72
#define R_STR   52       // fp32 reduction stride (52 dw -> conflict-free)

template <bool PRE>
__global__ __launch_bounds__(512, 4)
void winattn_mfma2(const float* __restrict__ x,
                   const float* __restrict__ mask, int nW,
                   const float* __restrict__ w_qkv,
                   const float* __restrict__ b_qkv,
                   const float* __restrict__ w_proj,
                   const float* __restrict__ b_proj,
                   const float* __restrict__ table,
                   const uint16_t* __restrict__ wpre,
                   float* __restrict__ out)
{
    __shared__ __align__(16) uint16_t lds[LDS_ELS];

    const int b    = blockIdx.x;
    const int t    = threadIdx.x;
    const int wave = t >> 6;
    const int lane = t & 63;
    const int q4   = lane >> 4;
    const int l16  = lane & 15;
    const float SCALE = 0.17677669529663687f;

    const uint16_t* wqkvT  = wpre;
    const uint16_t* wprojT = wpre + NQ;
    const float*    biasT  = (const float*)(wpre + NQ + NP);
    const float*    maskw  = mask + (size_t)(b % nW) * (NTOK * NTOK);

    // ---------- Phase 0: x -> swizzled bf16 tile (rows 0..48 only) ----------
    {
        const float4* xb = (const float4*)(x + (size_t)b * (NTOK * DIM));
        for (int i = t; i < NTOK * DIM / 4; i += 512) {
            float4 v = xb[i];
            int e = i * 4, row = e / DIM, col = e - row * DIM;
            ushort4 s;
            s.x = f2bf(v.x); s.y = f2bf(v.y); s.z = f2bf(v.z); s.w = f2bf(v.w);
            *(ushort4*)&lds[U_OFF + swz(row, col)] = s;
        }
    }
    __syncthreads();

    // ---------- Phase A: qkv GEMM, MFMA, 36 col-tiles over 8 waves ----------
    for (int ct = wave; ct < 36; ct += 8) {
        const int col = ct * 16 + l16;
        f32x4 acc[4];
        #pragma unroll
        for (int mt = 0; mt < 4; ++mt) acc[mt] = (f32x4){0.f, 0.f, 0.f, 0.f};

        #pragma unroll
        for (int kk = 0; kk < 6; ++kk) {
            short8 bfrag;
            if (PRE) {
                bfrag = *(const short8*)&wqkvT[(size_t)col * DIM + kk * 32 + q4 * 8];
            } else {
                union { uint16_t u[8]; short8 v; } tb;
                int k0 = kk * 32 + q4 * 8;
                #pragma unroll
                for (int j = 0; j < 8; ++j) tb.u[j] = f2bf(w_qkv[(size_t)(k0 + j) * QKV3 + col]);
                bfrag = tb.v;
            }
            #pragma unroll
            for (int mt = 0; mt < 4; ++mt) {
                short8 af = *(const short8*)&lds[U_OFF + swz(mt * 16 + l16, kk * 32 + q4 * 8)];
                acc[mt] = __builtin_amdgcn_mfma_f32_16x16x32_bf16(af, bfrag, acc[mt], 0, 0, 0);
            }
        }
        const float bias = b_qkv[col];
        if (col < DIM) {                       // Q (pre-scaled)
            #pragma unroll
            for (int mt = 0; mt < 4; ++mt)
                #pragma unroll
                for (int i = 0; i < 4; ++i) {
                    int tok = mt * 16 + q4 * 4 + i;
                    if (tok < NTOK)
                        lds[QS_OFF + swz(tok, col)] = f2bf((acc[mt][i] + bias) * SCALE);
                }
        } else if (col < 2 * DIM) {            // K
            const int kc = col - DIM;
            #pragma unroll
            for (int mt = 0; mt < 4; ++mt)
                #pragma unroll
                for (int i = 0; i < 4; ++i) {
                    int tok = mt * 16 + q4 * 4 + i;
                    if (tok < NTOK)
                        lds[KS_OFF + swz(tok, kc)] = f2bf(acc[mt][i] + bias);
                }
        } else {                               // V -> transposed [d][tok], zero pad tokens
            const int vc = col - 2 * DIM;
            #pragma unroll
            for (int mt = 0; mt < 4; ++mt)
                #pragma unroll
                for (int i = 0; i < 4; ++i) {
                    int tok = mt * 16 + q4 * 4 + i;
                    lds[VTA_OFF + vswz(vc, tok)] =
                        (tok < NTOK) ? f2bf(acc[mt][i] + bias) : (uint16_t)0;
                }
        }
    }
    __syncthreads();

    // ---------- Phase B: attention, zero barriers ----------
    const int mt    = wave & 3;
    const int hbase = (wave >> 2) * 3;
    uint16_t* paw = &lds[U_OFF + wave * (16 * PA_STR)];

    f32x4 pacc[12];
    #pragma unroll
    for (int nt = 0; nt < 12; ++nt) pacc[nt] = (f32x4){0.f, 0.f, 0.f, 0.f};

    for (int hi = 0; hi < 3; ++hi) {
        const int h = hbase + hi;
        // --- QK^T: 1x4 tiles ---
        short8 aq = *(const short8*)&lds[QS_OFF + swz(mt * 16 + l16, h * 32 + q4 * 8)];
        f32x4 lg[4];
        #pragma unroll
        for (int nt = 0; nt < 4; ++nt) {
            short8 bk = *(const short8*)&lds[KS_OFF + swz(nt * 16 + l16, h * 32 + q4 * 8)];
            f32x4 z = (f32x4){0.f, 0.f, 0.f, 0.f};
            lg[nt] = __builtin_amdgcn_mfma_f32_16x16x32_bf16(aq, bk, z, 0, 0, 0);
        }
        // --- + rel-pos bias + mask ---
        #pragma unroll
        for (int nt = 0; nt < 4; ++nt) {
            const int c = nt * 16 + l16;
            const int ca = (c < NTOK) ? c : (NTOK - 1);
            if (PRE) {
                f32x4 bb = *(const f32x4*)&biasT[(((h * 4 + mt) * 4 + nt) * 64 + lane) * 4];
                #pragma unroll
                for (int i = 0; i < 4; ++i) {
                    int r = mt * 16 + q4 * 4 + i;
                    int ra = (r < NTOK) ? r : (NTOK - 1);
                    lg[nt][i] += bb[i] + maskw[ra * NTOK + ca];
                }
            } else {
                #pragma unroll
                for (int i = 0; i < 4; ++i) {
                    int r = mt * 16 + q4 * 4 + i;
                    int ra = (r < NTOK) ? r : (NTOK - 1);
                    int rm = ra % 7, rd = ra / 7, cm = ca % 7, cd = ca / 7;
                    int bi = 13 * (rm - cm + 6) + (rd - cd + 6);
                    lg[nt][i] += table[bi * NHEADS + h] + maskw[ra * NTOK + ca];
                }
            }
        }
        // --- softmax fully in registers (rows live across 16 lanes x 4 regs) ---
        #pragma unroll
        for (int i = 0; i < 4; ++i) {
            float m = fmaxf(fmaxf(lg[0][i], lg[1][i]), lg[2][i]);
            if (l16 == 0) m = fmaxf(m, lg[3][i]);       // col 48 only
            m = fmaxf(m, __shfl_xor(m, 1));
            m = fmaxf(m, __shfl_xor(m, 2));
            m = fmaxf(m, __shfl_xor(m, 4));
            m = fmaxf(m, __shfl_xor(m, 8));
            float e0 = __expf(lg[0][i] - m);
            float e1 = __expf(lg[1][i] - m);
            float e2 = __expf(lg[2][i] - m);
            float e3 = (l16 == 0) ? __expf(lg[3][i] - m) : 0.f;
            float s = e0 + e1 + e2 + e3;
            s += __shfl_xor(s, 1);
            s += __shfl_xor(s, 2);
            s += __shfl_xor(s, 4);
            s += __shfl_xor(s, 8);
            const float inv = 1.f / s;
            lg[0][i] = e0 * inv; lg[1][i] = e1 * inv;
            lg[2][i] = e2 * inv; lg[3][i] = e3 * inv;
        }
        // --- P -> per-wave LDS (C-layout scatter; cols >= 49 are exact 0) ---
        #pragma unroll
        for (int nt = 0; nt < 4; ++nt)
            #pragma unroll
            for (int i = 0; i < 4; ++i)
                paw[(q4 * 4 + i) * PA_STR + nt * 16 + l16] = f2bf(lg[nt][i]);
        asm volatile("" ::: "memory");   // keep LDS write->read order (in-order per wave)

        // --- PV: out tile 16x32 ---
        f32x4 ov[2];
        ov[0] = (f32x4){0.f, 0.f, 0.f, 0.f};
        ov[1] = (f32x4){0.f, 0.f, 0.f, 0.f};
        #pragma unroll
        for (int kk = 0; kk < 2; ++kk) {
            short8 ap = *(const short8*)&paw[l16 * PA_STR + kk * 32 + q4 * 8];
            #pragma unroll
            for (int n2 = 0; n2 < 2; ++n2) {
                short8 bv = *(const short8*)&lds[VTA_OFF + vswz(h * 32 + n2 * 16 + l16,
                                                                kk * 32 + q4 * 8)];
                ov[n2] = __builtin_amdgcn_mfma_f32_16x16x32_bf16(ap, bv, ov[n2], 0, 0, 0);
            }
        }
        // --- transpose out-tile through the same private scratch ---
        asm volatile("" ::: "memory");
        #pragma unroll
        for (int n2 = 0; n2 < 2; ++n2)
            #pragma unroll
            for (int i = 0; i < 4; ++i)
                paw[(q4 * 4 + i) * PA_STR + n2 * 16 + l16] = f2bf(ov[n2][i]);
        asm volatile("" ::: "memory");

        // --- proj partial: acc += os_h(16x32) @ wproj[h-slice](32x192) ---
        short8 ap2 = *(const short8*)&paw[l16 * PA_STR + q4 * 8];
        #pragma unroll
        for (int nt = 0; nt < 12; ++nt) {
            short8 bw;
            if (PRE) {
                bw = *(const short8*)&wprojT[(size_t)(nt * 16 + l16) * DIM + h * 32 + q4 * 8];
            } else {
                union { uint16_t u[8]; short8 v; } tb;
                int k0 = h * 32 + q4 * 8;
                #pragma unroll
                for (int j = 0; j < 8; ++j)
                    tb.u[j] = f2bf(w_proj[(size_t)(k0 + j) * DIM + nt * 16 + l16]);
                bw = tb.v;
            }
            pacc[nt] = __builtin_amdgcn_mfma_f32_16x16x32_bf16(ap2, bw, pacc[nt], 0, 0, 0);
        }
    }
    __syncthreads();   // all tasks done; qs/ks/vta/pa dead

    // ---------- Phase C: cross-wave-pair reduction + writeout ----------
    float* R = (float*)lds;
    if (wave >= 4) {
        float* rw = R + (size_t)(mt * 64 + lane) * R_STR;
        #pragma unroll
        for (int nt = 0; nt < 12; ++nt)
            *(f32x4*)(rw + nt * 4) = pacc[nt];
    }
    __syncthreads();
    if (wave < 4) {
        const float* rr = R + (size_t)(mt * 64 + lane) * R_STR;
        float* ob = out + (size_t)b * (NTOK * DIM);
        #pragma unroll
        for (int nt = 0; nt < 12; ++nt) {
            f32x4 other = *(const f32x4*)(rr + nt * 4);
            const int c = nt * 16 + l16;
            const float bp = b_proj[c];
            #pragma unroll
            for (int i = 0; i < 4; ++i) {
                const int r = mt * 16 + q4 * 4 + i;
                if (r < NTOK) ob[r * DIM + c] = pacc[nt][i] + other[i] + bp;
            }
        }
    }
}

extern "C" void kernel_launch(void* const* d_in, const int* in_sizes, int n_in,
                              void* d_out, int out_size, void* d_ws, size_t ws_size,
                              hipStream_t stream) {
    const float* x      = (const float*)d_in[0];
    const float* mask   = (const float*)d_in[1];
    const float* w_qkv  = (const float*)d_in[2];
    const float* b_qkv  = (const float*)d_in[3];
    const float* w_proj = (const float*)d_in[4];
    const float* b_proj = (const float*)d_in[5];
    const float* table  = (const float*)d_in[6];
    float* out = (float*)d_out;

    const int nblocks = in_sizes[0] / (NTOK * DIM);   // 4096 windows
    const int nW      = in_sizes[1] / (NTOK * NTOK);  // 64
    const size_t WS_NEED = (size_t)(NQ + NP) * 2 + (size_t)NB * 4;  // 393216 B

    if (ws_size >= WS_NEED && d_ws != nullptr) {
        uint16_t* wpre = (uint16_t*)d_ws;
        const int total = NQ + NP + NB;
        prep_kernel<<<(total + 255) / 256, 256, 0, stream>>>(w_qkv, w_proj, table, wpre);
        winattn_mfma2<true><<<nblocks, 512, 0, stream>>>(x, mask, nW, w_qkv, b_qkv,
                                                         w_proj, b_proj, table, wpre, out);
    } else {
        winattn_mfma2<false><<<nblocks, 512, 0, stream>>>(x, mask, nW, w_qkv, b_qkv,
                                                          w_proj, b_proj, table, nullptr, out);
    }
}